// Round 12
// baseline (185.241 us; speedup 1.0000x reference)
//
#include <hip/hip_runtime.h>

// Attention_77730318123148 — B=2,S=2048,D=1024,H=16,HD=64. fp32 I/O, bf16 MFMA compute.
// R12: GEMMs re-tiled 64x64 (grid 1024 = 4 blocks/CU, was 2 — grid-limited occupancy
// was the stall source), XCD-aware n-strip decode (W/Wo L2-resident per XCD).
// attn (static-max, balanced grid, cp16 K/V) and prep unchanged from R11.

#define DD 1024
#define SS 2048
#define BB 2
#define HH 16
#define HD 64
#define QSCALE 0.18033688011112042f   // 0.125 * log2(e)
#define LSTR 88                        // attn QP row stride (ushorts)

typedef __attribute__((ext_vector_type(8))) short short8;   // 8 bf16 (A/B frag)
typedef __attribute__((ext_vector_type(4))) float float4v;  // C/D frag
typedef unsigned short ushort;
typedef unsigned int uint;

__device__ inline ushort f2bf(float f) {       // RNE (input conversion fidelity)
    union { float f; uint i; } v; v.f = f;
    uint r = v.i + 0x7FFF + ((v.i >> 16) & 1);
    return (ushort)(r >> 16);
}
#if __has_builtin(__builtin_amdgcn_cvt_pk_bf16_f32)
typedef __bf16 bf16x2 __attribute__((ext_vector_type(2)));
__device__ inline uint pack_bf2(float a, float b) {   // 1 inst, RNE
    union { bf16x2 v; uint u; } c;
    c.v = __builtin_amdgcn_cvt_pk_bf16_f32(a, b);
    return c.u;
}
#else
__device__ inline uint pack_bf2(float a, float b) {   // fallback: round-half-up
    union { float f; uint i; } x, y; x.f = a; y.f = b;
    return ((x.i + 0x8000u) >> 16) | (((y.i + 0x8000u) >> 16) << 16);
}
#endif

__device__ __forceinline__ void cp16(const ushort* g, ushort* l) {
    __builtin_amdgcn_global_load_lds((const __attribute__((address_space(1))) void*)g,
                                     (__attribute__((address_space(3))) void*)l,
                                     16, 0, 0);
}

// ---------------- prep: cvt x (4096 blk) | cvt Wo (1024 blk) | transpose W3 (768 blk) ----
__global__ __launch_bounds__(256) void prep(const float* __restrict__ x,
                                            const float* __restrict__ Wo,
                                            const float* __restrict__ Wq,
                                            const float* __restrict__ Wk,
                                            const float* __restrict__ Wv,
                                            ushort* __restrict__ xb,
                                            ushort* __restrict__ Wob,
                                            ushort* __restrict__ W3T) {
    __shared__ ushort T[64][65];
    int bid = blockIdx.x, t = threadIdx.x;
    if (bid < 5120) {
        const float* src; ushort* dst; int j;
        if (bid < 4096) { src = x;  dst = xb;  j = bid * 256 + t; }
        else            { src = Wo; dst = Wob; j = (bid - 4096) * 256 + t; }
        float4 v = ((const float4*)src)[j];
        ushort o[4] = { f2bf(v.x), f2bf(v.y), f2bf(v.z), f2bf(v.w) };
        ((uint2*)dst)[j] = *(const uint2*)o;
        return;
    }
    int i = bid - 5120;
    int z = i >> 8, h = (i >> 4) & 15, d0 = (i & 15) * 64;
    const float* W = z == 0 ? Wq : (z == 1 ? Wk : Wv);
    const float* Wh = W + h * DD * HD;
    ushort* Wt = W3T + ((size_t)z * HH + h) * HD * DD;
    #pragma unroll
    for (int s = 0; s < 4; s++) {
        int idx = t + s * 256;
        int d = idx >> 4, e4 = (idx & 15) * 4;
        float4 v = *(const float4*)(Wh + (d0 + d) * HD + e4);
        T[d][e4 + 0] = f2bf(v.x); T[d][e4 + 1] = f2bf(v.y);
        T[d][e4 + 2] = f2bf(v.z); T[d][e4 + 3] = f2bf(v.w);
    }
    __syncthreads();
    #pragma unroll
    for (int s = 0; s < 2; s++) {
        int idx = t + s * 256;
        int e = idx >> 3, d8 = (idx & 7) * 8;
        ushort tmp[8];
        #pragma unroll
        for (int j = 0; j < 8; j++) tmp[j] = T[d8 + j][e];
        *(uint4*)(Wt + e * DD + d0 + d8) = *(uint4*)tmp;
    }
}

// ---- QKV fused: xb[4096,1024] x {Wq,Wk,Wv}T (NT). M-tile 64, N-tile 64, BK=64.
// ---- Grid 1024 (4 blocks/CU). XCD decode: xcd=id&7 owns n-strips {2*xcd, 2*xcd+1}.
// ---- Wave w owns n-quarter w*16. z<2 swapped epilogue; z=2 -> vT direct.
__global__ __launch_bounds__(256, 4) void gemm_qkv(const ushort* __restrict__ xb,
                                                   const ushort* __restrict__ W3T,
                                                   const float* __restrict__ bq,
                                                   const float* __restrict__ bk,
                                                   const float* __restrict__ bv,
                                                   ushort* __restrict__ qb,
                                                   ushort* __restrict__ kb,
                                                   ushort* __restrict__ vT) {
    __shared__ ushort Al[64 * 64];       // 8 KB, XOR-swizzled chunks
    __shared__ ushort Bl[3][64 * 64];    // 3 x 8 KB, XOR-swizzled
    int id = blockIdx.x;
    int xcd = id & 7, p = id >> 3;               // p in [0,128)
    int n0 = (xcd * 2 + (p >> 6)) * 64;          // 16 n-strips, 2 per XCD
    int m0 = (p & 63) * 64;
    int t = threadIdx.x, lane = t & 63, w = t >> 6;
    int qm = lane >> 4, lm = lane & 15;

    const ushort* W0 = W3T + (size_t)n0 * DD;
    const ushort* W1 = W3T + (size_t)(HH * HD + n0) * DD;
    const ushort* W2 = W3T + (size_t)(2 * HH * HD + n0) * DD;

    float4v acc[3][4] = {};
    for (int k0 = 0; k0 < DD; k0 += 64) {
        __syncthreads();
        #pragma unroll
        for (int s = 0; s < 2; s++) {
            int c = t + s * 256;
            int row = c >> 3;
            int j = (c & 7) ^ (row & 7);   // XOR swizzle keeps cp16 lane-contiguous dst
            cp16(xb + (size_t)(m0 + row) * DD + k0 + j * 8, Al + c * 8);
            cp16(W0 + (size_t)row * DD + k0 + j * 8, Bl[0] + c * 8);
            cp16(W1 + (size_t)row * DD + k0 + j * 8, Bl[1] + c * 8);
            cp16(W2 + (size_t)row * DD + k0 + j * 8, Bl[2] + c * 8);
        }
        __syncthreads();
        #pragma unroll
        for (int h2 = 0; h2 < 2; h2++) {
            int sw = ((((h2 << 2) | qm) ^ (lm & 7)) << 3);
            short8 a[4];
            #pragma unroll
            for (int i = 0; i < 4; i++)
                a[i] = *(const short8*)(Al + ((i * 16 + lm) << 6) + sw);
            short8 b0 = *(const short8*)(Bl[0] + ((w * 16 + lm) << 6) + sw);
            short8 b1 = *(const short8*)(Bl[1] + ((w * 16 + lm) << 6) + sw);
            short8 b2 = *(const short8*)(Bl[2] + ((w * 16 + lm) << 6) + sw);
            #pragma unroll
            for (int i = 0; i < 4; i++) {
                acc[0][i] = __builtin_amdgcn_mfma_f32_16x16x32_bf16(b0, a[i], acc[0][i], 0, 0, 0);
                acc[1][i] = __builtin_amdgcn_mfma_f32_16x16x32_bf16(b1, a[i], acc[1][i], 0, 0, 0);
                acc[2][i] = __builtin_amdgcn_mfma_f32_16x16x32_bf16(a[i], b2, acc[2][i], 0, 0, 0);
            }
        }
    }
    // z=0 (Q, prescaled) and z=1 (K): swapped layout -> D row=n, col=m; 8B stores along n
    #pragma unroll
    for (int z = 0; z < 2; z++) {
        const float* bias = z == 0 ? bq : bk;
        ushort* Out = z == 0 ? qb : kb;
        float sc = z == 0 ? QSCALE : 1.0f;
        int nb = n0 + w * 16 + qm * 4;
        float4 b4 = *(const float4*)(bias + nb);
        #pragma unroll
        for (int i = 0; i < 4; i++) {
            int m = m0 + i * 16 + lm;
            uint2 o2;
            o2.x = pack_bf2((acc[z][i][0] + b4.x) * sc, (acc[z][i][1] + b4.y) * sc);
            o2.y = pack_bf2((acc[z][i][2] + b4.z) * sc, (acc[z][i][3] + b4.w) * sc);
            *(uint2*)(Out + (size_t)m * DD + nb) = o2;
        }
    }
    // z=2 (V): normal layout -> D row=m(s), col=n(e); vT 8B stores along s
    {
        int n = n0 + w * 16 + lm;
        int h = n >> 6, e = n & 63;
        float bb = bv[n];
        #pragma unroll
        for (int i = 0; i < 4; i++) {
            int m = m0 + i * 16 + qm * 4;
            int b_ = m >> 11, s = m & (SS - 1);
            uint2 o2;
            o2.x = pack_bf2(acc[2][i][0] + bb, acc[2][i][1] + bb);
            o2.y = pack_bf2(acc[2][i][2] + bb, acc[2][i][3] + bb);
            *(uint2*)(vT + ((size_t)(b_ * HH + h) * HD + e) * SS + s) = o2;
        }
    }
}

// -------- flash attention (causal), S^T form, static-max softmax (R11, unchanged).
__global__ __launch_bounds__(512, 4) void attn(const ushort* __restrict__ Q,
                                               const ushort* __restrict__ K,
                                               const ushort* __restrict__ VT,
                                               ushort* __restrict__ O) {
    __shared__ ushort QP[128][LSTR];
    __shared__ ushort Kl[2][64 * 64];
    __shared__ ushort Vl[2][64 * 64];
    int id = blockIdx.x;
    int bh = id & 31;
    int j5 = (id >> 5) & 7;
    int qt = (id < 256) ? (15 - 2 * j5) : (2 * j5);
    int b = bh >> 4, h = bh & 15;
    int m0 = qt * 128;
    int njt = 2 * (qt + 1);
    const ushort* Qp = Q + (size_t)b * SS * DD + h * HD;
    const ushort* Kp = K + (size_t)b * SS * DD + h * HD;
    const ushort* Vp = VT + (size_t)bh * HD * SS;
    int t = threadIdx.x, lane = t & 63, w = t >> 6;
    int qm = lane >> 4, lm = lane & 15;
    int row0 = t >> 3, colc = (t & 7) * 8;
    int srow = t >> 3;
    int sj = (t & 7) ^ (srow & 7);

    *(uint4*)(&QP[row0][colc])      = *(const uint4*)(Qp + (size_t)(m0 + row0) * DD + colc);
    *(uint4*)(&QP[row0 + 64][colc]) = *(const uint4*)(Qp + (size_t)(m0 + row0 + 64) * DD + colc);
    cp16(Kp + (size_t)srow * DD + sj * 8, Kl[0] + t * 8);
    cp16(Vp + (size_t)srow * SS + sj * 8, Vl[0] + t * 8);
    __syncthreads();

    short8 qf[2];
    qf[0] = *(const short8*)(&QP[w * 16 + lm][qm * 8]);
    qf[1] = *(const short8*)(&QP[w * 16 + lm][32 + qm * 8]);

    float4v o[4] = {};
    float li = 0.f;
    int cur = 0;
    int qg = m0 + w * 16 + lm;
    int swz = ((qm ^ (lm & 7)) << 3);
    int swz1 = (((4 | qm) ^ (lm & 7)) << 3);

    for (int jt = 0; jt < njt; jt++) {
        if (jt) __syncthreads();
        if (jt + 1 < njt) {
            int nn = (jt + 1) * 64;
            cp16(Kp + (size_t)(nn + srow) * DD + sj * 8, Kl[cur ^ 1] + t * 8);
            cp16(Vp + (size_t)srow * SS + nn + sj * 8, Vl[cur ^ 1] + t * 8);
        }

        float4v s[4] = {};
        #pragma unroll
        for (int j = 0; j < 4; j++) {
            short8 ak0 = *(const short8*)(Kl[cur] + ((j * 16 + lm) << 6) + swz);
            short8 ak1 = *(const short8*)(Kl[cur] + ((j * 16 + lm) << 6) + swz1);
            s[j] = __builtin_amdgcn_mfma_f32_16x16x32_bf16(ak0, qf[0], s[j], 0, 0, 0);
            s[j] = __builtin_amdgcn_mfma_f32_16x16x32_bf16(ak1, qf[1], s[j], 0, 0, 0);
        }
        if (jt >= 2 * qt) {
            #pragma unroll
            for (int j = 0; j < 4; j++)
                #pragma unroll
                for (int r = 0; r < 4; r++)
                    if (jt * 64 + j * 16 + qm * 4 + r > qg) s[j][r] = -__builtin_inff();
        }
        #pragma unroll
        for (int j = 0; j < 4; j++) {
            float p0 = __builtin_amdgcn_exp2f(s[j][0]);
            float p1 = __builtin_amdgcn_exp2f(s[j][1]);
            float p2 = __builtin_amdgcn_exp2f(s[j][2]);
            float p3 = __builtin_amdgcn_exp2f(s[j][3]);
            li += (p0 + p1) + (p2 + p3);
            uint2 u; u.x = pack_bf2(p0, p1); u.y = pack_bf2(p2, p3);
            *(uint2*)(&QP[w * 16 + lm][j * 16 + qm * 4]) = u;
        }
        asm volatile("s_waitcnt lgkmcnt(0)" ::: "memory");

        #pragma unroll
        for (int kc = 0; kc < 2; kc++) {
            short8 ap = *(const short8*)(&QP[w * 16 + lm][kc * 32 + qm * 8]);
            int so = kc ? swz1 : swz;
            #pragma unroll
            for (int jn = 0; jn < 4; jn++) {
                short8 av = *(const short8*)(Vl[cur] + ((jn * 16 + lm) << 6) + so);
                o[jn] = __builtin_amdgcn_mfma_f32_16x16x32_bf16(av, ap, o[jn], 0, 0, 0);
            }
        }
        cur ^= 1;
    }
    li += __shfl_xor(li, 16, 64);
    li += __shfl_xor(li, 32, 64);
    float inv = 1.f / li;
    ushort* Ob = O + ((size_t)b * SS + qg) * DD + h * HD;
    #pragma unroll
    for (int jn = 0; jn < 4; jn++) {
        uint2 u;
        u.x = pack_bf2(o[jn][0] * inv, o[jn][1] * inv);
        u.y = pack_bf2(o[jn][2] * inv, o[jn][3] * inv);
        *(uint2*)(Ob + jn * 16 + qm * 4) = u;
    }
}

// ---- out proj: wvb[4096,1024] x Wob^T (NT, 64x64, BK=64, grid 1024 = 4 blocks/CU) ----
__global__ __launch_bounds__(256, 4) void gemm_out(const ushort* __restrict__ X,
                                                   const ushort* __restrict__ Wob,
                                                   const float* __restrict__ bo,
                                                   float* __restrict__ Out) {
    __shared__ ushort Al[64 * 64];   // 8 KB swizzled
    __shared__ ushort Bl[64 * 64];   // 8 KB swizzled
    int id = blockIdx.x;
    int xcd = id & 7, p = id >> 3;
    int n0 = (xcd * 2 + (p >> 6)) * 64;
    int m0 = (p & 63) * 64;
    int t = threadIdx.x, lane = t & 63, w = t >> 6;
    int qm = lane >> 4, lm = lane & 15;

    float4v acc[4] = {};
    for (int k0 = 0; k0 < DD; k0 += 64) {
        __syncthreads();
        #pragma unroll
        for (int s = 0; s < 2; s++) {
            int c = t + s * 256;
            int row = c >> 3;
            int j = (c & 7) ^ (row & 7);
            cp16(X   + (size_t)(m0 + row) * DD + k0 + j * 8, Al + c * 8);
            cp16(Wob + (size_t)(n0 + row) * DD + k0 + j * 8, Bl + c * 8);
        }
        __syncthreads();
        #pragma unroll
        for (int h2 = 0; h2 < 2; h2++) {
            int sw = ((((h2 << 2) | qm) ^ (lm & 7)) << 3);
            short8 a[4];
            #pragma unroll
            for (int i = 0; i < 4; i++)
                a[i] = *(const short8*)(Al + ((i * 16 + lm) << 6) + sw);
            short8 b = *(const short8*)(Bl + ((w * 16 + lm) << 6) + sw);
            #pragma unroll
            for (int i = 0; i < 4; i++)   // swapped: D row=n, col=m
                acc[i] = __builtin_amdgcn_mfma_f32_16x16x32_bf16(b, a[i], acc[i], 0, 0, 0);
        }
    }
    int nb = n0 + w * 16 + qm * 4;
    float4 b4 = *(const float4*)(bo + nb);
    #pragma unroll
    for (int i = 0; i < 4; i++) {
        int m = m0 + i * 16 + lm;
        float4 st;
        st.x = acc[i][0] + b4.x;
        st.y = acc[i][1] + b4.y;
        st.z = acc[i][2] + b4.z;
        st.w = acc[i][3] + b4.w;
        *(float4*)(Out + (size_t)m * DD + nb) = st;
    }
}

extern "C" void kernel_launch(void* const* d_in, const int* in_sizes, int n_in,
                              void* d_out, int out_size, void* d_ws, size_t ws_size,
                              hipStream_t stream) {
    const float* x   = (const float*)d_in[0];
    const float* Wq  = (const float*)d_in[1];
    const float* bq  = (const float*)d_in[2];
    const float* Wk  = (const float*)d_in[3];
    const float* bk  = (const float*)d_in[4];
    const float* Wv_ = (const float*)d_in[5];
    const float* bv  = (const float*)d_in[6];
    const float* Wo  = (const float*)d_in[7];
    const float* bo  = (const float*)d_in[8];
    float* out = (float*)d_out;

    ushort* xb  = (ushort*)d_ws;
    ushort* W3T = xb  + (size_t)BB * SS * DD;
    ushort* Wob = W3T + (size_t)3 * HH * HD * DD;
    ushort* qb  = Wob + (size_t)DD * DD;
    ushort* kb  = qb + (size_t)BB * SS * DD;
    ushort* vT  = kb + (size_t)BB * SS * DD;
    ushort* wvb = vT + (size_t)BB * SS * DD;

    prep<<<dim3(5888), 256, 0, stream>>>(x, Wo, Wq, Wk, Wv_, xb, Wob, W3T);
    gemm_qkv<<<dim3(1024), 256, 0, stream>>>(xb, W3T, bq, bk, bv, qb, kb, vT);
    attn<<<dim3(512), 512, 0, stream>>>(qb, kb, vT, wvb);
    gemm_out<<<dim3(1024), 256, 0, stream>>>(wvb, Wob, bo, out);
}